// Round 7
// baseline (531.024 us; speedup 1.0000x reference)
//
#include <hip/hip_runtime.h>

typedef unsigned short u16;
typedef __attribute__((ext_vector_type(8))) short short8;
typedef __attribute__((ext_vector_type(4))) float floatx4;

#define MTOT    16384          // 4 * 64 * 64
#define PADIMG  (66 * 66)      // padded image pixels per batch
#define PADELEM (4 * PADIMG * 256)
#define PADB    ((size_t)PADELEM * 2)   // bytes, bf16
#define WSTEP   (256 * 2304)

__device__ __forceinline__ float bf2f(u16 u) {
  union { unsigned int i; float f; } c; c.i = ((unsigned int)u) << 16; return c.f;
}
__device__ __forceinline__ u16 f2bf(float f) {
  union { float f; unsigned int i; } c; c.f = f;
  unsigned int r = c.i + 0x7FFFu + ((c.i >> 16) & 1u);
  return (u16)(r >> 16);
}

__device__ __forceinline__ void gl_lds16(const void* g, void* l) {
  __builtin_amdgcn_global_load_lds(
      (const __attribute__((address_space(1))) void*)g,
      (__attribute__((address_space(3))) void*)l, 16, 0, 0);
}

// BK=32 LDS slot (u16 units): 4 chunks/row, XOR with (row>>1)&3  [R4: 0 conflicts]
__device__ __forceinline__ int lds_slot32(int row, int q) {
  return row * 32 + ((q ^ ((row >> 1) & 3)) << 3);
}
// BK=64 LDS slot: 8 chunks/row, XOR with row&7  [R5: 0 conflicts]
__device__ __forceinline__ int lds_slot64(int row, int q) {
  return row * 64 + ((q ^ (row & 7)) << 3);
}

// ---------------------------------------------------------------------------
// pack conv3x3 weights -> bf16 MFMA-fragment order per tensor:
// dst[((n/16)*72 + k/32)*512 + ((k>>3)&3)*128 + (n&15)*8 + (k&7)], k=(ky*3+kx)*256+c
__global__ void pack_w3_all(const float* __restrict__ cls_w, const float* __restrict__ reg_w,
                            const float* __restrict__ initw, const float* __restrict__ clsd,
                            const float* __restrict__ refd, u16* __restrict__ dst) {
  int blk = blockIdx.x;                       // 9 * 2304
  int w = blk / 2304;
  const float* src = (w < 3) ? cls_w + (size_t)w * WSTEP
                   : (w < 6) ? reg_w + (size_t)(w - 3) * WSTEP
                   : (w == 6) ? initw : (w == 7) ? clsd : refd;
  int idx = (blk - w * 2304) * 256 + threadIdx.x;   // 0 .. 589823 (dst offset)
  int e = idx & 7;
  int lane = (idx >> 3) & 63;
  int r = lane & 15, q = lane >> 4;
  int rest = idx >> 9;                        // 0..1151
  int kc = rest % 72, nt = rest / 72;
  int n = nt * 16 + r;
  int k = kc * 32 + q * 8 + e;
  int kk = k >> 8, c = k & 255;
  dst[(size_t)w * WSTEP + idx] = f2bf(src[(n * 256 + c) * 9 + kk]);
}

// pack three 1x1 weights [N][256] -> fragment order, N padded to 128
__global__ void pack_w1_all(const float* __restrict__ iw, const float* __restrict__ cw,
                            const float* __restrict__ rw, u16* __restrict__ dst) {
  int blk = blockIdx.x;                       // 384
  int wsel = blk >> 7;
  const float* src = wsel == 0 ? iw : wsel == 1 ? cw : rw;
  int nvalid = wsel == 1 ? 80 : 18;
  int idx = (blk & 127) * 256 + threadIdx.x;  // 0..32767
  int e = idx & 7;
  int lane = (idx >> 3) & 63;
  int r = lane & 15, q = lane >> 4;
  int rest = idx >> 9;                        // 0..63
  int kc = rest & 7, nt = rest >> 3;
  int n = nt * 16 + r;
  int k = kc * 32 + q * 8 + e;
  dst[(size_t)wsel * 32768 + idx] = f2bf(n < nvalid ? src[n * 256 + k] : 0.f);
}

// features fp32 NCHW [4][256][64][64] -> bf16 padded NHWC [4][66][66][256]
__global__ void nchw_to_pad_kernel(const float* __restrict__ src, u16* __restrict__ dst) {
  __shared__ float tile[64][65];
  int blk = blockIdx.x;                       // 4 * 64 * 4 = 1024
  int c0 = (blk & 3) * 64;
  int y  = (blk >> 2) & 63;
  int b  = blk >> 8;
  int t = threadIdx.x;
  #pragma unroll
  for (int i = 0; i < 16; ++i) {
    int lin = t + i * 256; int c = lin >> 6, x = lin & 63;
    tile[c][x] = src[((b * 256 + c0 + c) * 64 + y) * 64 + x];
  }
  __syncthreads();
  #pragma unroll
  for (int i = 0; i < 16; ++i) {
    int lin = t + i * 256; int x = lin >> 6, c = lin & 63;
    dst[((b * 66 + y + 1) * 66 + (x + 1)) * 256 + c0 + c] = f2bf(tile[c][x]);
  }
}

// ---------------------------------------------------------------------------
// paired GroupNorm apply: bf16 staging [2][M][256] + raw (s,s2) stats ->
// normalize+affine+relu -> padded bf16 NHWC per tower. grid 8192 x 256.
__global__ void __launch_bounds__(256)
gn_apply2(const u16* __restrict__ stage, const float2* __restrict__ st,
          const float* __restrict__ gwc, const float* __restrict__ gbc,
          const float* __restrict__ gwr, const float* __restrict__ gbr,
          u16* __restrict__ cdst, u16* __restrict__ rdst) {
  int tid = blockIdx.x * 256 + threadIdx.x;
  int tower = tid >> 20;
  int r = tid & 0xFFFFF;
  int m = r >> 6, c4 = (r & 63) << 2;
  ushort4 u = *(const ushort4*)(stage + ((size_t)tower << 22) + (size_t)m * 256 + c4);
  int b = m >> 12, p = m & 4095, y = p >> 6, x = p & 63;
  float2 ss = st[tower * 128 + b * 32 + (c4 >> 3)];
  float mu = ss.x * (1.f / 32768.f);
  float var = ss.y * (1.f / 32768.f) - mu * mu;
  float rinv = rsqrtf(var + 1e-5f);
  const float* gw = tower ? gwr : gwc;
  const float* gb = tower ? gbr : gbc;
  ushort4 o;
  o.x = f2bf(fmaxf((bf2f(u.x) - mu) * rinv * gw[c4 + 0] + gb[c4 + 0], 0.f));
  o.y = f2bf(fmaxf((bf2f(u.y) - mu) * rinv * gw[c4 + 1] + gb[c4 + 1], 0.f));
  o.z = f2bf(fmaxf((bf2f(u.z) - mu) * rinv * gw[c4 + 2] + gb[c4 + 2], 0.f));
  o.w = f2bf(fmaxf((bf2f(u.w) - mu) * rinv * gw[c4 + 3] + gb[c4 + 3], 0.f));
  u16* dst = tower ? rdst : cdst;
  *(ushort4*)(dst + ((size_t)((b * 66 + y + 1) * 66 + (x + 1)) * 256 + c4)) = o;
}

// ---------------------------------------------------------------------------
// bilinear sample, 4 ch/lane, 4 m/block -> A[m][kk*256+c] bf16.  grid 4096.
__global__ void __launch_bounds__(256)
dcn_sample_v(const u16* __restrict__ featpad, const float* __restrict__ pts,
             u16* __restrict__ A) {
  int t = threadIdx.x;
  int m = blockIdx.x * 4 + (t >> 6);
  int c4 = (t & 63) << 2;
  int b = m >> 12, p = m & 4095, y = p >> 6, x = p & 63;
  const float* pp = pts + (size_t)m * 18;
  const u16* fb = featpad + (size_t)b * PADIMG * 256;
  u16* am = A + (size_t)m * 2304 + c4;
  #pragma unroll
  for (int kk = 0; kk < 9; ++kk) {
    float py = (float)y + pp[2 * kk];
    float px = (float)x + pp[2 * kk + 1];
    float fy = floorf(py), fx = floorf(px);
    int y0 = (int)fy, x0 = (int)fx;
    float wy = py - fy, wx = px - fx;
    float w00 = (1.f - wy) * (1.f - wx), w01 = (1.f - wy) * wx;
    float w10 = wy * (1.f - wx), w11 = wy * wx;
    bool yok0 = (unsigned)y0 < 64u, yok1 = (unsigned)(y0 + 1) < 64u;
    bool xok0 = (unsigned)x0 < 64u, xok1 = (unsigned)(x0 + 1) < 64u;
    int base = ((y0 + 1) * 66 + (x0 + 1)) * 256 + c4;
    float r0 = 0.f, r1 = 0.f, r2 = 0.f, r3 = 0.f;
    if (yok0 & xok0) { ushort4 v = *(const ushort4*)(fb + base);
      r0 += w00 * bf2f(v.x); r1 += w00 * bf2f(v.y); r2 += w00 * bf2f(v.z); r3 += w00 * bf2f(v.w); }
    if (yok0 & xok1) { ushort4 v = *(const ushort4*)(fb + base + 256);
      r0 += w01 * bf2f(v.x); r1 += w01 * bf2f(v.y); r2 += w01 * bf2f(v.z); r3 += w01 * bf2f(v.w); }
    if (yok1 & xok0) { ushort4 v = *(const ushort4*)(fb + base + 66 * 256);
      r0 += w10 * bf2f(v.x); r1 += w10 * bf2f(v.y); r2 += w10 * bf2f(v.z); r3 += w10 * bf2f(v.w); }
    if (yok1 & xok1) { ushort4 v = *(const ushort4*)(fb + base + 66 * 256 + 256);
      r0 += w11 * bf2f(v.x); r1 += w11 * bf2f(v.y); r2 += w11 * bf2f(v.z); r3 += w11 * bf2f(v.w); }
    ushort4 o; o.x = f2bf(r0); o.y = f2bf(r1); o.z = f2bf(r2); o.w = f2bf(r3);
    *(ushort4*)(am + kk * 256) = o;
  }
}

// ---------------------------------------------------------------------------
// GEMM: C[M,N] = A[M,K] * W[N,K]^T.  128xBN tile, BK in {32,64}, 4 waves.
// A staged via global_load_lds; B read DIRECTLY from fragment-packed global
// (one coalesced dwordx4 per wave per fragment; no LDS, no barrier dep).
// Block decode: [NPAIR==2: pair=blk&1, blk>>=1]  bm=blk&127, bn=blk>>7.
// EP 0: bf16 staging + GN (s,s2) atomics; EP 1: +bias,relu->bf16;
// EP 2: relu->bf16; EP 3: +bias(+addpts)(+ptsout) -> fp32 NCHW out at cb.
template <int AMODE, int EP, int KSZ, int BN, int BK, int NPAIR>
__global__ void __launch_bounds__(256)
gemm_kernel(const u16* __restrict__ A0, const u16* __restrict__ A1,
            const u16* __restrict__ W0, const u16* __restrict__ W1,
            const float* __restrict__ bias0, const float* __restrict__ bias1,
            u16* __restrict__ outb0, u16* __restrict__ outb1,
            float2* __restrict__ st0, float2* __restrict__ st1,
            float* __restrict__ outf,
            const float* __restrict__ addpts0, const float* __restrict__ addpts1,
            float* __restrict__ ptsout0, float* __restrict__ ptsout1,
            int nv0, int nv1, int cb0, int cb1) {
  constexpr int NJ = BN / 32;                 // 16-col accum tiles per wave
  constexpr int NKC = KSZ / 32;               // 32-k chunks in K
  __shared__ u16 As[128 * BK];
  int t = threadIdx.x;
  int blk = blockIdx.x;
  int pair = 0;
  if constexpr (NPAIR == 2) { pair = blk & 1; blk >>= 1; }
  const u16* A        = pair ? A1 : A0;
  const u16* Wp       = pair ? W1 : W0;
  const float* bias   = pair ? bias1 : bias0;
  u16* outb           = pair ? outb1 : outb0;
  float2* st          = pair ? st1 : st0;
  const float* addpts = pair ? addpts1 : addpts0;
  float* ptsout       = pair ? ptsout1 : ptsout0;
  int nv = pair ? nv1 : nv0;
  int cb = pair ? cb1 : cb0;

  int bm = blk & 127, bn = blk >> 7;
  int lane = t & 63, wave = t >> 6;
  int wm = (wave & 1) << 6;
  int wn = (wave >> 1) * (BN / 2);
  int quad = lane >> 4, r16 = lane & 15;

  // B fragment bases: tile index t_j = bn*(BN/16) + wn/16 + j
  const u16* wfrag = Wp + ((size_t)(bn * (BN / 16) + (wn >> 4)) * NKC) * 512 + lane * 8;

  floatx4 acc[4][NJ];
  #pragma unroll
  for (int i = 0; i < 4; ++i)
    #pragma unroll
    for (int j = 0; j < NJ; ++j)
      acc[i][j] = (floatx4){0.f, 0.f, 0.f, 0.f};

  if constexpr (BK == 64) {
    // A staging: 8 chunks/row; thread t covers (row = 32k + t>>3, slot = t&7)
    int sub = t >> 3;                 // 0..31
    int cq = (t & 7) ^ (sub & 7);     // XOR-swizzled global chunk for this slot
    int abase[4];
    #pragma unroll
    for (int k = 0; k < 4; ++k) {
      int m = bm * 128 + k * 32 + sub;
      if constexpr (AMODE == 1) {
        int b = m >> 12, p = m & 4095;
        abase[k] = ((b * 66 + (p >> 6)) * 66 + (p & 63)) * 256 + cq * 8;
      } else {
        abase[k] = m * KSZ + cq * 8;
      }
    }

    for (int s = 0; s < KSZ / 64; ++s) {
      int d;
      if constexpr (AMODE == 1) {
        int kk = s >> 2;                 // 0..8
        int c0 = (s & 3) << 6;           // 0..192
        int ky = kk / 3, kx = kk - ky * 3;
        d = ((ky * 66 + kx) << 8) + c0;
      } else {
        d = s * 64;
      }
      #pragma unroll
      for (int k = 0; k < 4; ++k)
        gl_lds16(A + abase[k] + d, &As[k * 2048 + t * 8]);
      __syncthreads();
      // B fragments direct from global (coalesced, L1/L2-resident)
      short8 bfr[2][NJ];
      #pragma unroll
      for (int ks = 0; ks < 2; ++ks)
        #pragma unroll
        for (int j = 0; j < NJ; ++j)
          bfr[ks][j] = *(const short8*)(wfrag + ((size_t)j * NKC + (s * 2 + ks)) * 512);
      short8 af[2][4];
      #pragma unroll
      for (int ks = 0; ks < 2; ++ks)
        #pragma unroll
        for (int i = 0; i < 4; ++i)
          af[ks][i] = *(const short8*)&As[lds_slot64(wm + i * 16 + r16, ks * 4 + quad)];
      #pragma unroll
      for (int ks = 0; ks < 2; ++ks)
        #pragma unroll
        for (int i = 0; i < 4; ++i)
          #pragma unroll
          for (int j = 0; j < NJ; ++j)
            acc[i][j] = __builtin_amdgcn_mfma_f32_16x16x32_bf16(af[ks][i], bfr[ks][j], acc[i][j], 0, 0, 0);
      __syncthreads();
    }
  } else {
    // BK=32 path: 4 chunks/row
    int row = t >> 2;
    int chunkS = (t & 3) ^ ((t >> 3) & 3);
    int m0 = bm * 128 + row, m1 = m0 + 64;
    int abase0, abase1;
    if constexpr (AMODE == 1) {
      int b0 = m0 >> 12, p0 = m0 & 4095;
      int b1 = m1 >> 12, p1 = m1 & 4095;
      abase0 = ((b0 * 66 + (p0 >> 6)) * 66 + (p0 & 63)) * 256 + chunkS * 8;
      abase1 = ((b1 * 66 + (p1 >> 6)) * 66 + (p1 & 63)) * 256 + chunkS * 8;
    } else {
      abase0 = m0 * KSZ + chunkS * 8;
      abase1 = m1 * KSZ + chunkS * 8;
    }

    for (int s = 0; s < KSZ / 32; ++s) {
      int d;
      if constexpr (AMODE == 1) {
        int kk = s >> 3;
        int c0 = (s & 7) << 5;
        int ky = kk / 3, kx = kk - ky * 3;
        d = ((ky * 66 + kx) << 8) + c0;
      } else {
        d = s * 32;
      }
      gl_lds16(A + abase0 + d, &As[t * 8]);
      gl_lds16(A + abase1 + d, &As[2048 + t * 8]);
      __syncthreads();
      short8 bfr[NJ];
      #pragma unroll
      for (int j = 0; j < NJ; ++j)
        bfr[j] = *(const short8*)(wfrag + ((size_t)j * NKC + s) * 512);
      short8 af[4];
      #pragma unroll
      for (int i = 0; i < 4; ++i)
        af[i] = *(const short8*)&As[lds_slot32(wm + i * 16 + r16, quad)];
      #pragma unroll
      for (int i = 0; i < 4; ++i)
        #pragma unroll
        for (int j = 0; j < NJ; ++j)
          acc[i][j] = __builtin_amdgcn_mfma_f32_16x16x32_bf16(af[i], bfr[j], acc[i][j], 0, 0, 0);
      __syncthreads();
    }
  }

  #pragma unroll
  for (int j = 0; j < NJ; ++j) {
    int gn = bn * BN + wn + j * 16 + r16;
    float s = 0.f, s2 = 0.f;
    #pragma unroll
    for (int i = 0; i < 4; ++i) {
      #pragma unroll
      for (int r = 0; r < 4; ++r) {
        int gm = bm * 128 + wm + i * 16 + quad * 4 + r;
        float v = acc[i][j][r];
        if constexpr (EP == 0) {
          outb[(size_t)gm * 256 + gn] = f2bf(v);
          s += v; s2 += v * v;
        } else if constexpr (EP == 1) {
          outb[(size_t)gm * 256 + gn] = f2bf(fmaxf(v + bias[gn], 0.f));
        } else if constexpr (EP == 2) {
          outb[(size_t)gm * 256 + gn] = f2bf(fmaxf(v, 0.f));
        } else {
          if (gn < nv) {
            v += bias[gn];
            if (addpts) v += addpts[(size_t)gm * 18 + gn];
            if (ptsout) ptsout[(size_t)gm * 18 + gn] = v;
            int bb = gm >> 12, p = gm & 4095;
            outf[(size_t)((bb * 116 + cb + gn) << 12) + p] = v;
          }
        }
      }
    }
    if constexpr (EP == 0) {
      // reduce lanes differing in bits {0,1,2,4,5}; keep bit3 (8-ch group)
      s += __shfl_xor(s, 1);  s2 += __shfl_xor(s2, 1);
      s += __shfl_xor(s, 2);  s2 += __shfl_xor(s2, 2);
      s += __shfl_xor(s, 4);  s2 += __shfl_xor(s2, 4);
      s += __shfl_xor(s, 16); s2 += __shfl_xor(s2, 16);
      s += __shfl_xor(s, 32); s2 += __shfl_xor(s2, 32);
      if ((lane & 55) == 0) {
        float2* sp = st + ((bm >> 5) * 32) + (gn >> 3);
        atomicAdd(&sp->x, s);
        atomicAdd(&sp->y, s2);
      }
    }
  }
}

// ---------------------------------------------------------------------------
extern "C" void kernel_launch(void* const* d_in, const int* in_sizes, int n_in,
                              void* d_out, int out_size, void* d_ws, size_t ws_size,
                              hipStream_t stream) {
  (void)in_sizes; (void)n_in; (void)out_size;
  const float* features    = (const float*)d_in[0];
  const float* cls_w       = (const float*)d_in[1];
  const float* reg_w       = (const float*)d_in[2];
  const float* cls_gn_w    = (const float*)d_in[3];
  const float* cls_gn_b    = (const float*)d_in[4];
  const float* reg_gn_w    = (const float*)d_in[5];
  const float* reg_gn_b    = (const float*)d_in[6];
  const float* init_conv_w = (const float*)d_in[7];
  const float* init_conv_b = (const float*)d_in[8];
  const float* init_out_w  = (const float*)d_in[9];
  const float* init_out_b  = (const float*)d_in[10];
  const float* cls_dcn_w   = (const float*)d_in[11];
  const float* cls_out_w   = (const float*)d_in[12];
  const float* cls_out_b   = (const float*)d_in[13];
  const float* ref_dcn_w   = (const float*)d_in[14];
  const float* ref_out_w   = (const float*)d_in[15];
  const float* ref_out_b   = (const float*)d_in[16];
  float* out = (float*)d_out;

  char* ws = (char*)d_ws;
  size_t off = 0;
  auto alloc = [&](size_t bytes) {
    char* p = ws + off;
    off += (bytes + 255) & ~(size_t)255;
    return p;
  };
  u16* wpack      = (u16*)alloc((size_t)9 * WSTEP * 2);
  u16* w1         = (u16*)alloc((size_t)3 * 32768 * 2);
  u16* xpad       = (u16*)alloc(PADB);     // 5 pads contiguous for one memset
  u16* cpadA      = (u16*)alloc(PADB);
  u16* cpadB      = (u16*)alloc(PADB);
  u16* rpadA      = (u16*)alloc(PADB);
  u16* rpadB      = (u16*)alloc(PADB);
  float* ptsbuf   = (float*)alloc((size_t)MTOT * 18 * 4);
  float2* statsAll= (float2*)alloc(3 * 256 * sizeof(float2));
  u16* initf      = (u16*)alloc((size_t)MTOT * 256 * 2);
  u16* dcnout     = (u16*)alloc((size_t)2 * MTOT * 256 * 2);
  // union region: cstage [2][M][256] bf16 (towers) then adcn [M][2304] bf16 (dcn)
  char* unionReg  = alloc((size_t)MTOT * 2304 * 2);
  u16* cstage     = (u16*)unionReg;
  u16* adcn       = (u16*)unionReg;
  u16* adcn2      = (u16*)alloc((size_t)MTOT * 2304 * 2);   // only used if ws allows
  bool paired_dcn = (off <= ws_size);

  (void)hipMemsetAsync(xpad, 0, 5 * PADB, stream);
  (void)hipMemsetAsync(statsAll, 0, 3 * 256 * sizeof(float2), stream);

  pack_w3_all<<<9 * 2304, 256, 0, stream>>>(cls_w, reg_w, init_conv_w, cls_dcn_w, ref_dcn_w, wpack);
  pack_w1_all<<<384, 256, 0, stream>>>(init_out_w, cls_out_w, ref_out_w, w1);
  nchw_to_pad_kernel<<<1024, 256, 0, stream>>>(features, xpad);

  // towers, paired (cls=pair0, reg=pair1): 3 layers of conv3x3+GN+relu
  const u16* curC = xpad; const u16* curR = xpad;
  u16* nxtC = cpadA; u16* altC = cpadB;
  u16* nxtR = rpadA; u16* altR = rpadB;
  for (int i = 0; i < 3; ++i) {
    gemm_kernel<1, 0, 2304, 128, 64, 2><<<512, 256, 0, stream>>>(
        curC, curR, wpack + (size_t)i * WSTEP, wpack + (size_t)(3 + i) * WSTEP,
        nullptr, nullptr, cstage, cstage + (size_t)MTOT * 256,
        statsAll + i * 256, statsAll + i * 256 + 128,
        nullptr, nullptr, nullptr, nullptr, nullptr, 0, 0, 0, 0);
    gn_apply2<<<8192, 256, 0, stream>>>(cstage, statsAll + i * 256,
        cls_gn_w + i * 256, cls_gn_b + i * 256, reg_gn_w + i * 256, reg_gn_b + i * 256,
        nxtC, nxtR);
    curC = nxtC; { u16* tmp = nxtC; nxtC = altC; altC = tmp; }
    curR = nxtR; { u16* tmp = nxtR; nxtR = altR; altR = tmp; }
  }
  const u16* cls_feat = curC;   // cpadA
  const u16* reg_feat = curR;   // rpadA

  // init branch: relu(conv3x3 + b) -> initf; 1x1 -> pts_init (out ch 80..97 + ptsbuf)
  gemm_kernel<1, 1, 2304, 64, 64, 1><<<512, 256, 0, stream>>>(
      reg_feat, nullptr, wpack + (size_t)6 * WSTEP, nullptr,
      init_conv_b, nullptr, initf, nullptr, nullptr, nullptr,
      nullptr, nullptr, nullptr, nullptr, nullptr, 0, 0, 0, 0);
  gemm_kernel<0, 3, 256, 128, 32, 1><<<128, 256, 0, stream>>>(
      initf, nullptr, w1, nullptr, init_out_b, nullptr,
      nullptr, nullptr, nullptr, nullptr, out,
      nullptr, nullptr, ptsbuf, nullptr, 18, 0, 80, 0);

  if (paired_dcn) {
    dcn_sample_v<<<4096, 256, 0, stream>>>(cls_feat, ptsbuf, adcn);
    dcn_sample_v<<<4096, 256, 0, stream>>>(reg_feat, ptsbuf, adcn2);
    gemm_kernel<0, 2, 2304, 128, 64, 2><<<512, 256, 0, stream>>>(
        adcn, adcn2, wpack + (size_t)7 * WSTEP, wpack + (size_t)8 * WSTEP,
        nullptr, nullptr, dcnout, dcnout + (size_t)MTOT * 256, nullptr, nullptr,
        nullptr, nullptr, nullptr, nullptr, nullptr, 0, 0, 0, 0);
  } else {
    dcn_sample_v<<<4096, 256, 0, stream>>>(cls_feat, ptsbuf, adcn);
    gemm_kernel<0, 2, 2304, 64, 64, 1><<<512, 256, 0, stream>>>(
        adcn, nullptr, wpack + (size_t)7 * WSTEP, nullptr,
        nullptr, nullptr, dcnout, nullptr, nullptr, nullptr,
        nullptr, nullptr, nullptr, nullptr, nullptr, 0, 0, 0, 0);
    dcn_sample_v<<<4096, 256, 0, stream>>>(reg_feat, ptsbuf, adcn);
    gemm_kernel<0, 2, 2304, 64, 64, 1><<<512, 256, 0, stream>>>(
        adcn, nullptr, wpack + (size_t)8 * WSTEP, nullptr,
        nullptr, nullptr, dcnout + (size_t)MTOT * 256, nullptr, nullptr, nullptr,
        nullptr, nullptr, nullptr, nullptr, nullptr, 0, 0, 0, 0);
  }

  // final heads, paired: cls (80 ch at 0), refine (18 ch at 98, + pts_init)
  gemm_kernel<0, 3, 256, 128, 32, 2><<<256, 256, 0, stream>>>(
      dcnout, dcnout + (size_t)MTOT * 256, w1 + 32768, w1 + 2 * 32768,
      cls_out_b, ref_out_b, nullptr, nullptr, nullptr, nullptr, out,
      nullptr, ptsbuf, nullptr, nullptr, 80, 18, 0, 98);
}

// Round 9
// 497.555 us; speedup vs baseline: 1.0673x; 1.0673x over previous
//
#include <hip/hip_runtime.h>

typedef unsigned short u16;
typedef __attribute__((ext_vector_type(8))) short short8;
typedef __attribute__((ext_vector_type(4))) float floatx4;

#define MTOT    16384          // 4 * 64 * 64
#define PADIMG  (66 * 66)      // padded image pixels per batch
#define PADELEM (4 * PADIMG * 256)
#define PADB    ((size_t)PADELEM * 2)   // bytes, bf16 (multiple of 256 -> allocs contiguous)
#define WSTEP   (256 * 2304)

__device__ __forceinline__ float bf2f(u16 u) {
  union { unsigned int i; float f; } c; c.i = ((unsigned int)u) << 16; return c.f;
}
__device__ __forceinline__ u16 f2bf(float f) {
  union { float f; unsigned int i; } c; c.f = f;
  unsigned int r = c.i + 0x7FFFu + ((c.i >> 16) & 1u);
  return (u16)(r >> 16);
}

__device__ __forceinline__ void gl_lds16(const void* g, void* l) {
  __builtin_amdgcn_global_load_lds(
      (const __attribute__((address_space(1))) void*)g,
      (__attribute__((address_space(3))) void*)l, 16, 0, 0);
}

// BK=32 LDS slot (u16 units): 4 chunks/row, XOR with (row>>1)&3  [R4: 0 conflicts]
__device__ __forceinline__ int lds_slot32(int row, int q) {
  return row * 32 + ((q ^ ((row >> 1) & 3)) << 3);
}
// BK=64 LDS slot: 8 chunks/row, XOR with row&7  [R5: 0 conflicts]
__device__ __forceinline__ int lds_slot64(int row, int q) {
  return row * 64 + ((q ^ (row & 7)) << 3);
}

// ---------------------------------------------------------------------------
// zero the 1-px halo ring of the 5 contiguous padded buffers [5][4][66][66][256]
__global__ void ring_zero(u16* __restrict__ pads) {
  int idx = blockIdx.x * 256 + threadIdx.x;   // grid 1300 -> 332800 = 5*4*260*64
  int c4 = (idx & 63) << 2;
  int r = idx >> 6;                           // 0..5199
  int pix = r % 260;
  int ib = r / 260;                           // buf*4 + batch, 0..19
  int y, x;
  if (pix < 66)       { y = 0;  x = pix; }
  else if (pix < 132) { y = 65; x = pix - 66; }
  else if (pix < 196) { y = pix - 132 + 1; x = 0; }
  else                { y = pix - 196 + 1; x = 65; }
  size_t o = (((size_t)ib * PADIMG) + y * 66 + x) * 256 + c4;
  *(ushort4*)(pads + o) = (ushort4){0, 0, 0, 0};
}

// ---------------------------------------------------------------------------
// merged pack: conv3x3 weights (flat [w][o][(ky*3+kx)*256+c]) + 1x1 weights
__global__ void pack_all(const float* __restrict__ cls_w, const float* __restrict__ reg_w,
                         const float* __restrict__ initw, const float* __restrict__ clsd,
                         const float* __restrict__ refd,
                         const float* __restrict__ iw, const float* __restrict__ cw,
                         const float* __restrict__ rw,
                         u16* __restrict__ dst3, u16* __restrict__ dst1) {
  int blk = blockIdx.x;                       // 9*2304 + 384 = 21120
  if (blk < 9 * 2304) {
    int w = blk / 2304;
    const float* src = (w < 3) ? cls_w + (size_t)w * WSTEP
                     : (w < 6) ? reg_w + (size_t)(w - 3) * WSTEP
                     : (w == 6) ? initw : (w == 7) ? clsd : refd;
    int idx = (blk - w * 2304) * 256 + threadIdx.x;
    int o = idx / 2304, r = idx - o * 2304;
    int kk = r >> 8, c = r & 255;
    dst3[(size_t)w * WSTEP + idx] = f2bf(src[(o * 256 + c) * 9 + kk]);
  } else {
    blk -= 9 * 2304;                          // 0..383
    int wsel = blk >> 7;
    const float* src = wsel == 0 ? iw : wsel == 1 ? cw : rw;
    int nvalid = wsel == 1 ? 80 : 18;
    int idx = (blk & 127) * 256 + threadIdx.x;
    int o = idx >> 8, c = idx & 255;
    dst1[(size_t)wsel * 32768 + idx] = f2bf(o < nvalid ? src[o * 256 + c] : 0.f);
  }
}

// features fp32 NCHW [4][256][64][64] -> bf16 padded NHWC [4][66][66][256]
__global__ void nchw_to_pad_kernel(const float* __restrict__ src, u16* __restrict__ dst) {
  __shared__ float tile[64][65];
  int blk = blockIdx.x;                       // 4 * 64 * 4 = 1024
  int c0 = (blk & 3) * 64;
  int y  = (blk >> 2) & 63;
  int b  = blk >> 8;
  int t = threadIdx.x;
  #pragma unroll
  for (int i = 0; i < 16; ++i) {
    int lin = t + i * 256; int c = lin >> 6, x = lin & 63;
    tile[c][x] = src[((b * 256 + c0 + c) * 64 + y) * 64 + x];
  }
  __syncthreads();
  #pragma unroll
  for (int i = 0; i < 16; ++i) {
    int lin = t + i * 256; int x = lin >> 6, c = lin & 63;
    dst[((b * 66 + y + 1) * 66 + (x + 1)) * 256 + c0 + c] = f2bf(tile[c][x]);
  }
}

// ---------------------------------------------------------------------------
// paired GroupNorm apply: bf16 staging [2][M][256] + raw (s,s2) stats ->
// normalize+affine+relu -> padded bf16 NHWC per tower. grid 8192 x 256.
__global__ void __launch_bounds__(256)
gn_apply2(const u16* __restrict__ stage, const float2* __restrict__ st,
          const float* __restrict__ gwc, const float* __restrict__ gbc,
          const float* __restrict__ gwr, const float* __restrict__ gbr,
          u16* __restrict__ cdst, u16* __restrict__ rdst) {
  int tid = blockIdx.x * 256 + threadIdx.x;
  int tower = tid >> 20;
  int r = tid & 0xFFFFF;
  int m = r >> 6, c4 = (r & 63) << 2;
  ushort4 u = *(const ushort4*)(stage + ((size_t)tower << 22) + (size_t)m * 256 + c4);
  int b = m >> 12, p = m & 4095, y = p >> 6, x = p & 63;
  float2 ss = st[tower * 128 + b * 32 + (c4 >> 3)];
  float mu = ss.x * (1.f / 32768.f);
  float var = ss.y * (1.f / 32768.f) - mu * mu;
  float rinv = rsqrtf(var + 1e-5f);
  const float* gw = tower ? gwr : gwc;
  const float* gb = tower ? gbr : gbc;
  ushort4 o;
  o.x = f2bf(fmaxf((bf2f(u.x) - mu) * rinv * gw[c4 + 0] + gb[c4 + 0], 0.f));
  o.y = f2bf(fmaxf((bf2f(u.y) - mu) * rinv * gw[c4 + 1] + gb[c4 + 1], 0.f));
  o.z = f2bf(fmaxf((bf2f(u.z) - mu) * rinv * gw[c4 + 2] + gb[c4 + 2], 0.f));
  o.w = f2bf(fmaxf((bf2f(u.w) - mu) * rinv * gw[c4 + 3] + gb[c4 + 3], 0.f));
  u16* dst = tower ? rdst : cdst;
  *(ushort4*)(dst + ((size_t)((b * 66 + y + 1) * 66 + (x + 1)) * 256 + c4)) = o;
}

// ---------------------------------------------------------------------------
// bilinear sample for both towers in one launch. blk<4096 -> (featC, AC),
// else (featR, AR). 4 ch/lane, 4 m/block -> A[m][kk*256+c] bf16.
__global__ void __launch_bounds__(256)
dcn_sample2(const u16* __restrict__ featC, const u16* __restrict__ featR,
            const float* __restrict__ pts,
            u16* __restrict__ AC, u16* __restrict__ AR) {
  int blk = blockIdx.x;
  const u16* featpad = blk < 4096 ? featC : featR;
  u16* A = blk < 4096 ? AC : AR;
  int mblk = blk & 4095;
  int t = threadIdx.x;
  int m = mblk * 4 + (t >> 6);
  int c4 = (t & 63) << 2;
  int b = m >> 12, p = m & 4095, y = p >> 6, x = p & 63;
  const float* pp = pts + (size_t)m * 18;
  const u16* fb = featpad + (size_t)b * PADIMG * 256;
  u16* am = A + (size_t)m * 2304 + c4;
  #pragma unroll
  for (int kk = 0; kk < 9; ++kk) {
    float py = (float)y + pp[2 * kk];
    float px = (float)x + pp[2 * kk + 1];
    float fy = floorf(py), fx = floorf(px);
    int y0 = (int)fy, x0 = (int)fx;
    float wy = py - fy, wx = px - fx;
    float w00 = (1.f - wy) * (1.f - wx), w01 = (1.f - wy) * wx;
    float w10 = wy * (1.f - wx), w11 = wy * wx;
    bool yok0 = (unsigned)y0 < 64u, yok1 = (unsigned)(y0 + 1) < 64u;
    bool xok0 = (unsigned)x0 < 64u, xok1 = (unsigned)(x0 + 1) < 64u;
    int base = ((y0 + 1) * 66 + (x0 + 1)) * 256 + c4;
    float r0 = 0.f, r1 = 0.f, r2 = 0.f, r3 = 0.f;
    if (yok0 & xok0) { ushort4 v = *(const ushort4*)(fb + base);
      r0 += w00 * bf2f(v.x); r1 += w00 * bf2f(v.y); r2 += w00 * bf2f(v.z); r3 += w00 * bf2f(v.w); }
    if (yok0 & xok1) { ushort4 v = *(const ushort4*)(fb + base + 256);
      r0 += w01 * bf2f(v.x); r1 += w01 * bf2f(v.y); r2 += w01 * bf2f(v.z); r3 += w01 * bf2f(v.w); }
    if (yok1 & xok0) { ushort4 v = *(const ushort4*)(fb + base + 66 * 256);
      r0 += w10 * bf2f(v.x); r1 += w10 * bf2f(v.y); r2 += w10 * bf2f(v.z); r3 += w10 * bf2f(v.w); }
    if (yok1 & xok1) { ushort4 v = *(const ushort4*)(fb + base + 66 * 256 + 256);
      r0 += w11 * bf2f(v.x); r1 += w11 * bf2f(v.y); r2 += w11 * bf2f(v.z); r3 += w11 * bf2f(v.w); }
    ushort4 o; o.x = f2bf(r0); o.y = f2bf(r1); o.z = f2bf(r2); o.w = f2bf(r3);
    *(ushort4*)(am + kk * 256) = o;
  }
}

// ---------------------------------------------------------------------------
// GEMM: C[M,N] = A[M,K] * W[N,K]^T.  128xBN tile, BK in {32,64}, 4 waves.
// [R6-verified source] Block decode: [NPAIR==2: pair=blk&1, blk>>=1]
// bm=blk&127, bn=blk>>7.  AMODE 0: flat A; AMODE 1: implicit conv3x3.
// EP 0: bf16 staging + GN (s,s2) atomics; EP 1: +bias,relu; EP 2: relu;
// EP 3: +bias (+addpts) (+ptsout) -> fp32 NCHW d_out slice at cb, gn < nv.
template <int AMODE, int EP, int KSZ, int BN, int BK, int NPAIR>
__global__ void __launch_bounds__(256)
gemm_kernel(const u16* __restrict__ A0, const u16* __restrict__ A1,
            const u16* __restrict__ W0, const u16* __restrict__ W1,
            const float* __restrict__ bias0, const float* __restrict__ bias1,
            u16* __restrict__ outb0, u16* __restrict__ outb1,
            float2* __restrict__ st0, float2* __restrict__ st1,
            float* __restrict__ outf,
            const float* __restrict__ addpts0, const float* __restrict__ addpts1,
            float* __restrict__ ptsout0, float* __restrict__ ptsout1,
            int nv0, int nv1, int cb0, int cb1) {
  constexpr int NJ = BN / 32;                 // 16-col accum tiles per wave
  __shared__ u16 As[128 * BK];
  __shared__ u16 Bs[BN * BK];
  int t = threadIdx.x;
  int blk = blockIdx.x;
  int pair = 0;
  if constexpr (NPAIR == 2) { pair = blk & 1; blk >>= 1; }
  const u16* A        = pair ? A1 : A0;
  const u16* Wp       = pair ? W1 : W0;
  const float* bias   = pair ? bias1 : bias0;
  u16* outb           = pair ? outb1 : outb0;
  float2* st          = pair ? st1 : st0;
  const float* addpts = pair ? addpts1 : addpts0;
  float* ptsout       = pair ? ptsout1 : ptsout0;
  int nv = pair ? nv1 : nv0;
  int cb = pair ? cb1 : cb0;

  int bm = blk & 127, bn = blk >> 7;
  int lane = t & 63, wave = t >> 6;
  int wm = (wave & 1) << 6;
  int wn = (wave >> 1) * (BN / 2);
  int quad = lane >> 4, r16 = lane & 15;

  floatx4 acc[4][NJ];
  #pragma unroll
  for (int i = 0; i < 4; ++i)
    #pragma unroll
    for (int j = 0; j < NJ; ++j)
      acc[i][j] = (floatx4){0.f, 0.f, 0.f, 0.f};

  if constexpr (BK == 64) {
    // staging: 8 chunks/row; thread t covers (row = 32k + t>>3, slot = t&7)
    int sub = t >> 3;                 // 0..31
    int cq = (t & 7) ^ (sub & 7);     // XOR-swizzled global chunk for this slot
    int abase[4];
    #pragma unroll
    for (int k = 0; k < 4; ++k) {
      int m = bm * 128 + k * 32 + sub;
      if constexpr (AMODE == 1) {
        int b = m >> 12, p = m & 4095;
        abase[k] = ((b * 66 + (p >> 6)) * 66 + (p & 63)) * 256 + cq * 8;
      } else {
        abase[k] = m * KSZ + cq * 8;
      }
    }
    const u16* wg = Wp + (size_t)(bn * BN + sub) * KSZ + cq * 8;

    for (int s = 0; s < KSZ / 64; ++s) {
      int d;
      if constexpr (AMODE == 1) {
        int kk = s >> 2;                 // 0..8
        int c0 = (s & 3) << 6;           // 0..192
        int ky = kk / 3, kx = kk - ky * 3;
        d = ((ky * 66 + kx) << 8) + c0;
      } else {
        d = s * 64;
      }
      #pragma unroll
      for (int k = 0; k < 4; ++k)
        gl_lds16(A + abase[k] + d, &As[k * 2048 + t * 8]);
      #pragma unroll
      for (int k = 0; k < BN / 32; ++k)
        gl_lds16(wg + (size_t)(k * 32) * KSZ + s * 64, &Bs[k * 2048 + t * 8]);
      __syncthreads();
      short8 af[2][4], bfr[2][NJ];
      #pragma unroll
      for (int ks = 0; ks < 2; ++ks) {
        #pragma unroll
        for (int i = 0; i < 4; ++i)
          af[ks][i] = *(const short8*)&As[lds_slot64(wm + i * 16 + r16, ks * 4 + quad)];
        #pragma unroll
        for (int j = 0; j < NJ; ++j)
          bfr[ks][j] = *(const short8*)&Bs[lds_slot64(wn + j * 16 + r16, ks * 4 + quad)];
      }
      #pragma unroll
      for (int ks = 0; ks < 2; ++ks)
        #pragma unroll
        for (int i = 0; i < 4; ++i)
          #pragma unroll
          for (int j = 0; j < NJ; ++j)
            acc[i][j] = __builtin_amdgcn_mfma_f32_16x16x32_bf16(af[ks][i], bfr[ks][j], acc[i][j], 0, 0, 0);
      __syncthreads();
    }
  } else {
    // BK=32 path (R4-verified): 4 chunks/row
    int row = t >> 2;
    int chunkS = (t & 3) ^ ((t >> 3) & 3);
    int m0 = bm * 128 + row, m1 = m0 + 64;
    int abase0, abase1;
    if constexpr (AMODE == 1) {
      int b0 = m0 >> 12, p0 = m0 & 4095;
      int b1 = m1 >> 12, p1 = m1 & 4095;
      abase0 = ((b0 * 66 + (p0 >> 6)) * 66 + (p0 & 63)) * 256 + chunkS * 8;
      abase1 = ((b1 * 66 + (p1 >> 6)) * 66 + (p1 & 63)) * 256 + chunkS * 8;
    } else {
      abase0 = m0 * KSZ + chunkS * 8;
      abase1 = m1 * KSZ + chunkS * 8;
    }
    const u16* wg = Wp + (size_t)(bn * BN + row) * KSZ + chunkS * 8;

    for (int s = 0; s < KSZ / 32; ++s) {
      int d;
      if constexpr (AMODE == 1) {
        int kk = s >> 3;
        int c0 = (s & 7) << 5;
        int ky = kk / 3, kx = kk - ky * 3;
        d = ((ky * 66 + kx) << 8) + c0;
      } else {
        d = s * 32;
      }
      gl_lds16(A + abase0 + d, &As[t * 8]);
      gl_lds16(A + abase1 + d, &As[2048 + t * 8]);
      gl_lds16(wg + s * 32, &Bs[t * 8]);
      if constexpr (BN == 128)
        gl_lds16(wg + (size_t)64 * KSZ + s * 32, &Bs[2048 + t * 8]);
      __syncthreads();
      short8 af[4], bfr[NJ];
      #pragma unroll
      for (int i = 0; i < 4; ++i)
        af[i] = *(const short8*)&As[lds_slot32(wm + i * 16 + r16, quad)];
      #pragma unroll
      for (int j = 0; j < NJ; ++j)
        bfr[j] = *(const short8*)&Bs[lds_slot32(wn + j * 16 + r16, quad)];
      #pragma unroll
      for (int i = 0; i < 4; ++i)
        #pragma unroll
        for (int j = 0; j < NJ; ++j)
          acc[i][j] = __builtin_amdgcn_mfma_f32_16x16x32_bf16(af[i], bfr[j], acc[i][j], 0, 0, 0);
      __syncthreads();
    }
  }

  #pragma unroll
  for (int j = 0; j < NJ; ++j) {
    int gn = bn * BN + wn + j * 16 + r16;
    float s = 0.f, s2 = 0.f;
    #pragma unroll
    for (int i = 0; i < 4; ++i) {
      #pragma unroll
      for (int r = 0; r < 4; ++r) {
        int gm = bm * 128 + wm + i * 16 + quad * 4 + r;
        float v = acc[i][j][r];
        if constexpr (EP == 0) {
          outb[(size_t)gm * 256 + gn] = f2bf(v);
          s += v; s2 += v * v;
        } else if constexpr (EP == 1) {
          outb[(size_t)gm * 256 + gn] = f2bf(fmaxf(v + bias[gn], 0.f));
        } else if constexpr (EP == 2) {
          outb[(size_t)gm * 256 + gn] = f2bf(fmaxf(v, 0.f));
        } else {
          if (gn < nv) {
            v += bias[gn];
            if (addpts) v += addpts[(size_t)gm * 18 + gn];
            if (ptsout) ptsout[(size_t)gm * 18 + gn] = v;
            int bb = gm >> 12, p = gm & 4095;
            outf[(size_t)((bb * 116 + cb + gn) << 12) + p] = v;
          }
        }
      }
    }
    if constexpr (EP == 0) {
      // reduce lanes differing in bits {0,1,2,4,5}; keep bit3 (8-ch group)
      s += __shfl_xor(s, 1);  s2 += __shfl_xor(s2, 1);
      s += __shfl_xor(s, 2);  s2 += __shfl_xor(s2, 2);
      s += __shfl_xor(s, 4);  s2 += __shfl_xor(s2, 4);
      s += __shfl_xor(s, 16); s2 += __shfl_xor(s2, 16);
      s += __shfl_xor(s, 32); s2 += __shfl_xor(s2, 32);
      if ((lane & 55) == 0) {
        float2* sp = st + ((bm >> 5) * 32) + (gn >> 3);
        atomicAdd(&sp->x, s);
        atomicAdd(&sp->y, s2);
      }
    }
  }
}

// ---------------------------------------------------------------------------
extern "C" void kernel_launch(void* const* d_in, const int* in_sizes, int n_in,
                              void* d_out, int out_size, void* d_ws, size_t ws_size,
                              hipStream_t stream) {
  (void)in_sizes; (void)n_in; (void)out_size;
  const float* features    = (const float*)d_in[0];
  const float* cls_w       = (const float*)d_in[1];
  const float* reg_w       = (const float*)d_in[2];
  const float* cls_gn_w    = (const float*)d_in[3];
  const float* cls_gn_b    = (const float*)d_in[4];
  const float* reg_gn_w    = (const float*)d_in[5];
  const float* reg_gn_b    = (const float*)d_in[6];
  const float* init_conv_w = (const float*)d_in[7];
  const float* init_conv_b = (const float*)d_in[8];
  const float* init_out_w  = (const float*)d_in[9];
  const float* init_out_b  = (const float*)d_in[10];
  const float* cls_dcn_w   = (const float*)d_in[11];
  const float* cls_out_w   = (const float*)d_in[12];
  const float* cls_out_b   = (const float*)d_in[13];
  const float* ref_dcn_w   = (const float*)d_in[14];
  const float* ref_out_w   = (const float*)d_in[15];
  const float* ref_out_b   = (const float*)d_in[16];
  float* out = (float*)d_out;

  char* ws = (char*)d_ws;
  size_t off = 0;
  auto alloc = [&](size_t bytes) {
    char* p = ws + off;
    off += (bytes + 255) & ~(size_t)255;
    return p;
  };
  u16* wpack      = (u16*)alloc((size_t)9 * WSTEP * 2);
  u16* w1         = (u16*)alloc((size_t)3 * 32768 * 2);
  u16* xpad       = (u16*)alloc(PADB);     // 5 pads contiguous (PADB % 256 == 0)
  u16* cpadA      = (u16*)alloc(PADB);
  u16* cpadB      = (u16*)alloc(PADB);
  u16* rpadA      = (u16*)alloc(PADB);
  u16* rpadB      = (u16*)alloc(PADB);
  float* ptsbuf   = (float*)alloc((size_t)MTOT * 18 * 4);
  float2* statsAll= (float2*)alloc(3 * 256 * sizeof(float2));
  u16* initf      = (u16*)alloc((size_t)MTOT * 256 * 2);
  u16* dcnout     = (u16*)alloc((size_t)2 * MTOT * 256 * 2);
  // union region: cstage [2][M][256] bf16 (towers) then adcn [M][2304] bf16 (dcn)
  char* unionReg  = alloc((size_t)MTOT * 2304 * 2);
  u16* cstage     = (u16*)unionReg;
  u16* adcn       = (u16*)unionReg;
  u16* adcn2      = (u16*)alloc((size_t)MTOT * 2304 * 2);   // only used if ws allows
  bool paired_dcn = (off <= ws_size);

  // halo rings (2.7 MB) instead of 89 MB memset; stats counters zeroed
  ring_zero<<<1300, 256, 0, stream>>>(xpad);
  (void)hipMemsetAsync(statsAll, 0, 3 * 256 * sizeof(float2), stream);

  pack_all<<<21120, 256, 0, stream>>>(cls_w, reg_w, init_conv_w, cls_dcn_w, ref_dcn_w,
                                      init_out_w, cls_out_w, ref_out_w, wpack, w1);
  nchw_to_pad_kernel<<<1024, 256, 0, stream>>>(features, xpad);

  // towers, paired (cls=pair0, reg=pair1): 3 layers of conv3x3+GN+relu
  const u16* curC = xpad; const u16* curR = xpad;
  u16* nxtC = cpadA; u16* altC = cpadB;
  u16* nxtR = rpadA; u16* altR = rpadB;
  for (int i = 0; i < 3; ++i) {
    gemm_kernel<1, 0, 2304, 64, 64, 2><<<1024, 256, 0, stream>>>(
        curC, curR, wpack + (size_t)i * WSTEP, wpack + (size_t)(3 + i) * WSTEP,
        nullptr, nullptr, cstage, cstage + (size_t)MTOT * 256,
        statsAll + i * 256, statsAll + i * 256 + 128,
        nullptr, nullptr, nullptr, nullptr, nullptr, 0, 0, 0, 0);
    gn_apply2<<<8192, 256, 0, stream>>>(cstage, statsAll + i * 256,
        cls_gn_w + i * 256, cls_gn_b + i * 256, reg_gn_w + i * 256, reg_gn_b + i * 256,
        nxtC, nxtR);
    curC = nxtC; { u16* tmp = nxtC; nxtC = altC; altC = tmp; }
    curR = nxtR; { u16* tmp = nxtR; nxtR = altR; altR = tmp; }
  }
  const u16* cls_feat = curC;   // cpadA
  const u16* reg_feat = curR;   // rpadA

  // init branch: relu(conv3x3 + b) -> initf; 1x1 -> pts_init (out ch 80..97 + ptsbuf)
  gemm_kernel<1, 1, 2304, 64, 64, 1><<<512, 256, 0, stream>>>(
      reg_feat, nullptr, wpack + (size_t)6 * WSTEP, nullptr,
      init_conv_b, nullptr, initf, nullptr, nullptr, nullptr,
      nullptr, nullptr, nullptr, nullptr, nullptr, 0, 0, 0, 0);
  gemm_kernel<0, 3, 256, 128, 32, 1><<<128, 256, 0, stream>>>(
      initf, nullptr, w1, nullptr, init_out_b, nullptr,
      nullptr, nullptr, nullptr, nullptr, out,
      nullptr, nullptr, ptsbuf, nullptr, 18, 0, 80, 0);

  if (paired_dcn) {
    dcn_sample2<<<8192, 256, 0, stream>>>(cls_feat, reg_feat, ptsbuf, adcn, adcn2);
    gemm_kernel<0, 2, 2304, 64, 64, 2><<<1024, 256, 0, stream>>>(
        adcn, adcn2, wpack + (size_t)7 * WSTEP, wpack + (size_t)8 * WSTEP,
        nullptr, nullptr, dcnout, dcnout + (size_t)MTOT * 256, nullptr, nullptr,
        nullptr, nullptr, nullptr, nullptr, nullptr, 0, 0, 0, 0);
  } else {
    dcn_sample2<<<4096, 256, 0, stream>>>(cls_feat, cls_feat, ptsbuf, adcn, adcn);
    gemm_kernel<0, 2, 2304, 64, 64, 1><<<512, 256, 0, stream>>>(
        adcn, nullptr, wpack + (size_t)7 * WSTEP, nullptr,
        nullptr, nullptr, dcnout, nullptr, nullptr, nullptr,
        nullptr, nullptr, nullptr, nullptr, nullptr, 0, 0, 0, 0);
    dcn_sample2<<<4096, 256, 0, stream>>>(reg_feat, reg_feat, ptsbuf, adcn, adcn);
    gemm_kernel<0, 2, 2304, 64, 64, 1><<<512, 256, 0, stream>>>(
        adcn, nullptr, wpack + (size_t)8 * WSTEP, nullptr,
        nullptr, nullptr, dcnout + (size_t)MTOT * 256, nullptr, nullptr, nullptr,
        nullptr, nullptr, nullptr, nullptr, nullptr, 0, 0, 0, 0);
  }

  // final heads, paired: cls (80 ch at 0), refine (18 ch at 98, + pts_init)
  gemm_kernel<0, 3, 256, 128, 32, 2><<<256, 256, 0, stream>>>(
      dcnout, dcnout + (size_t)MTOT * 256, w1 + 32768, w1 + 2 * 32768,
      cls_out_b, ref_out_b, nullptr, nullptr, nullptr, nullptr, out,
      nullptr, ptsbuf, nullptr, nullptr, 80, 18, 0, 98);
}

// Round 10
// 480.810 us; speedup vs baseline: 1.1044x; 1.0348x over previous
//
#include <hip/hip_runtime.h>

typedef unsigned short u16;
typedef __attribute__((ext_vector_type(8))) short short8;
typedef __attribute__((ext_vector_type(4))) float floatx4;

#define MTOT    16384          // 4 * 64 * 64
#define PADIMG  (66 * 66)      // padded image pixels per batch
#define PADELEM (4 * PADIMG * 256)
#define PADB    ((size_t)PADELEM * 2)   // bytes, bf16 (multiple of 256 -> allocs contiguous)
#define WSTEP   (256 * 2304)

__device__ __forceinline__ float bf2f(u16 u) {
  union { unsigned int i; float f; } c; c.i = ((unsigned int)u) << 16; return c.f;
}
__device__ __forceinline__ u16 f2bf(float f) {
  union { float f; unsigned int i; } c; c.f = f;
  unsigned int r = c.i + 0x7FFFu + ((c.i >> 16) & 1u);
  return (u16)(r >> 16);
}

__device__ __forceinline__ void gl_lds16(const void* g, void* l) {
  __builtin_amdgcn_global_load_lds(
      (const __attribute__((address_space(1))) void*)g,
      (__attribute__((address_space(3))) void*)l, 16, 0, 0);
}

// BK=32 LDS slot (u16 units): 4 chunks/row, XOR with (row>>1)&3  [R4: 0 conflicts]
__device__ __forceinline__ int lds_slot32(int row, int q) {
  return row * 32 + ((q ^ ((row >> 1) & 3)) << 3);
}
// BK=64 LDS slot: 8 chunks/row, XOR with row&7  [R5: 0 conflicts]
__device__ __forceinline__ int lds_slot64(int row, int q) {
  return row * 64 + ((q ^ (row & 7)) << 3);
}

// ---------------------------------------------------------------------------
// merged setup kernel (all regions disjoint):
//   blk < 20736          : pack conv3x3 weights -> flat [w][o][(ky*3+kx)*256+c]
//   blk < 21120          : pack 1x1 weights -> [128 zero-pad][256] x3
//   blk < 22144 (1024)   : features NCHW fp32 -> bf16 padded NHWC interior
//   blk < 23444 (1300)   : zero halo rings of the 5 padded buffers
__global__ void setup_all(const float* __restrict__ cls_w, const float* __restrict__ reg_w,
                          const float* __restrict__ initw, const float* __restrict__ clsd,
                          const float* __restrict__ refd,
                          const float* __restrict__ iw, const float* __restrict__ cw,
                          const float* __restrict__ rw,
                          const float* __restrict__ features,
                          u16* __restrict__ dst3, u16* __restrict__ dst1,
                          u16* __restrict__ pads) {
  int blk = blockIdx.x;
  int t = threadIdx.x;
  if (blk < 20736) {
    int w = blk / 2304;
    const float* src = (w < 3) ? cls_w + (size_t)w * WSTEP
                     : (w < 6) ? reg_w + (size_t)(w - 3) * WSTEP
                     : (w == 6) ? initw : (w == 7) ? clsd : refd;
    int idx = (blk - w * 2304) * 256 + t;
    int o = idx / 2304, r = idx - o * 2304;
    int kk = r >> 8, c = r & 255;
    dst3[(size_t)w * WSTEP + idx] = f2bf(src[(o * 256 + c) * 9 + kk]);
  } else if (blk < 21120) {
    int bb = blk - 20736;                     // 0..383
    int wsel = bb >> 7;
    const float* src = wsel == 0 ? iw : wsel == 1 ? cw : rw;
    int nvalid = wsel == 1 ? 80 : 18;
    int idx = (bb & 127) * 256 + t;
    int o = idx >> 8, c = idx & 255;
    dst1[(size_t)wsel * 32768 + idx] = f2bf(o < nvalid ? src[o * 256 + c] : 0.f);
  } else if (blk < 22144) {
    __shared__ float tile[64][65];
    int bb = blk - 21120;                     // 0..1023
    int c0 = (bb & 3) * 64;
    int y  = (bb >> 2) & 63;
    int b  = bb >> 8;
    #pragma unroll
    for (int i = 0; i < 16; ++i) {
      int lin = t + i * 256; int c = lin >> 6, x = lin & 63;
      tile[c][x] = features[((b * 256 + c0 + c) * 64 + y) * 64 + x];
    }
    __syncthreads();
    #pragma unroll
    for (int i = 0; i < 16; ++i) {
      int lin = t + i * 256; int x = lin >> 6, c = lin & 63;
      pads[((b * 66 + y + 1) * 66 + (x + 1)) * 256 + c0 + c] = f2bf(tile[c][x]);
    }
  } else {
    int idx = (blk - 22144) * 256 + t;        // 0..332799 = 5*4*260*64
    int c4 = (idx & 63) << 2;
    int r = idx >> 6;
    int pix = r % 260;
    int ib = r / 260;                         // buf*4 + batch, 0..19
    int y, x;
    if (pix < 66)       { y = 0;  x = pix; }
    else if (pix < 132) { y = 65; x = pix - 66; }
    else if (pix < 196) { y = pix - 132 + 1; x = 0; }
    else                { y = pix - 196 + 1; x = 65; }
    size_t o = (((size_t)ib * PADIMG) + y * 66 + x) * 256 + c4;
    *(ushort4*)(pads + o) = (ushort4){0, 0, 0, 0};
  }
}

// ---------------------------------------------------------------------------
// paired GroupNorm apply: bf16 staging [2][M][256] + raw (s,s2) stats ->
// normalize+affine+relu -> padded bf16 NHWC per tower. grid 8192 x 256.
__global__ void __launch_bounds__(256)
gn_apply2(const u16* __restrict__ stage, const float2* __restrict__ st,
          const float* __restrict__ gwc, const float* __restrict__ gbc,
          const float* __restrict__ gwr, const float* __restrict__ gbr,
          u16* __restrict__ cdst, u16* __restrict__ rdst) {
  int tid = blockIdx.x * 256 + threadIdx.x;
  int tower = tid >> 20;
  int r = tid & 0xFFFFF;
  int m = r >> 6, c4 = (r & 63) << 2;
  ushort4 u = *(const ushort4*)(stage + ((size_t)tower << 22) + (size_t)m * 256 + c4);
  int b = m >> 12, p = m & 4095, y = p >> 6, x = p & 63;
  float2 ss = st[tower * 128 + b * 32 + (c4 >> 3)];
  float mu = ss.x * (1.f / 32768.f);
  float var = ss.y * (1.f / 32768.f) - mu * mu;
  float rinv = rsqrtf(var + 1e-5f);
  const float* gw = tower ? gwr : gwc;
  const float* gb = tower ? gbr : gbc;
  ushort4 o;
  o.x = f2bf(fmaxf((bf2f(u.x) - mu) * rinv * gw[c4 + 0] + gb[c4 + 0], 0.f));
  o.y = f2bf(fmaxf((bf2f(u.y) - mu) * rinv * gw[c4 + 1] + gb[c4 + 1], 0.f));
  o.z = f2bf(fmaxf((bf2f(u.z) - mu) * rinv * gw[c4 + 2] + gb[c4 + 2], 0.f));
  o.w = f2bf(fmaxf((bf2f(u.w) - mu) * rinv * gw[c4 + 3] + gb[c4 + 3], 0.f));
  u16* dst = tower ? rdst : cdst;
  *(ushort4*)(dst + ((size_t)((b * 66 + y + 1) * 66 + (x + 1)) * 256 + c4)) = o;
}

// ---------------------------------------------------------------------------
// bilinear sample, both towers. 16 lanes/pixel, 16 ch/lane (chunk c covers
// ch c*64 + l*4 -> every ld/st is 128 B contiguous per pixel-group).
// grid 2048: blk<1024 -> (featC,AC), else (featR,AR); 16 m per block.
__global__ void __launch_bounds__(256)
dcn_sample2(const u16* __restrict__ featC, const u16* __restrict__ featR,
            const float* __restrict__ pts,
            u16* __restrict__ AC, u16* __restrict__ AR) {
  int blk = blockIdx.x;
  const u16* featpad = blk < 1024 ? featC : featR;
  u16* A = blk < 1024 ? AC : AR;
  int mblk = blk & 1023;
  int t = threadIdx.x;
  int m = mblk * 16 + (t >> 4);
  int l = t & 15;
  int b = m >> 12, p = m & 4095, y = p >> 6, x = p & 63;
  const float* pp = pts + (size_t)m * 18;
  const u16* fb = featpad + (size_t)b * PADIMG * 256 + l * 4;
  u16* am = A + (size_t)m * 2304 + l * 4;
  #pragma unroll
  for (int kk = 0; kk < 9; ++kk) {
    float py = (float)y + pp[2 * kk];
    float px = (float)x + pp[2 * kk + 1];
    float fy = floorf(py), fx = floorf(px);
    int y0 = (int)fy, x0 = (int)fx;
    float wy = py - fy, wx = px - fx;
    float w00 = (1.f - wy) * (1.f - wx), w01 = (1.f - wy) * wx;
    float w10 = wy * (1.f - wx), w11 = wy * wx;
    bool yok0 = (unsigned)y0 < 64u, yok1 = (unsigned)(y0 + 1) < 64u;
    bool xok0 = (unsigned)x0 < 64u, xok1 = (unsigned)(x0 + 1) < 64u;
    const u16* base = fb + ((y0 + 1) * 66 + (x0 + 1)) * 256;
    float r[16];
    #pragma unroll
    for (int i = 0; i < 16; ++i) r[i] = 0.f;
    if (yok0 & xok0) {
      #pragma unroll
      for (int c = 0; c < 4; ++c) { ushort4 v = *(const ushort4*)(base + c * 64);
        r[c*4+0] += w00 * bf2f(v.x); r[c*4+1] += w00 * bf2f(v.y);
        r[c*4+2] += w00 * bf2f(v.z); r[c*4+3] += w00 * bf2f(v.w); } }
    if (yok0 & xok1) {
      #pragma unroll
      for (int c = 0; c < 4; ++c) { ushort4 v = *(const ushort4*)(base + 256 + c * 64);
        r[c*4+0] += w01 * bf2f(v.x); r[c*4+1] += w01 * bf2f(v.y);
        r[c*4+2] += w01 * bf2f(v.z); r[c*4+3] += w01 * bf2f(v.w); } }
    if (yok1 & xok0) {
      #pragma unroll
      for (int c = 0; c < 4; ++c) { ushort4 v = *(const ushort4*)(base + 66 * 256 + c * 64);
        r[c*4+0] += w10 * bf2f(v.x); r[c*4+1] += w10 * bf2f(v.y);
        r[c*4+2] += w10 * bf2f(v.z); r[c*4+3] += w10 * bf2f(v.w); } }
    if (yok1 & xok1) {
      #pragma unroll
      for (int c = 0; c < 4; ++c) { ushort4 v = *(const ushort4*)(base + 67 * 256 + c * 64);
        r[c*4+0] += w11 * bf2f(v.x); r[c*4+1] += w11 * bf2f(v.y);
        r[c*4+2] += w11 * bf2f(v.z); r[c*4+3] += w11 * bf2f(v.w); } }
    #pragma unroll
    for (int c = 0; c < 4; ++c) {
      ushort4 o;
      o.x = f2bf(r[c*4+0]); o.y = f2bf(r[c*4+1]);
      o.z = f2bf(r[c*4+2]); o.w = f2bf(r[c*4+3]);
      *(ushort4*)(am + kk * 256 + c * 64) = o;
    }
  }
}

// ---------------------------------------------------------------------------
// GEMM: C[M,N] = A[M,K] * W[N,K]^T.  128xBN tile, BK in {32,64}, 4 waves.
// [R6-verified source] Block decode: [NPAIR==2: pair=blk&1, blk>>=1]
// bm=blk&127, bn=blk>>7.  AMODE 0: flat A; AMODE 1: implicit conv3x3.
// EP 0: bf16 staging + GN (s,s2) atomics; EP 1: +bias,relu; EP 2: relu;
// EP 3: +bias (+addpts) (+ptsout) -> fp32 NCHW d_out slice at cb, gn < nv.
template <int AMODE, int EP, int KSZ, int BN, int BK, int NPAIR>
__global__ void __launch_bounds__(256)
gemm_kernel(const u16* __restrict__ A0, const u16* __restrict__ A1,
            const u16* __restrict__ W0, const u16* __restrict__ W1,
            const float* __restrict__ bias0, const float* __restrict__ bias1,
            u16* __restrict__ outb0, u16* __restrict__ outb1,
            float2* __restrict__ st0, float2* __restrict__ st1,
            float* __restrict__ outf,
            const float* __restrict__ addpts0, const float* __restrict__ addpts1,
            float* __restrict__ ptsout0, float* __restrict__ ptsout1,
            int nv0, int nv1, int cb0, int cb1) {
  constexpr int NJ = BN / 32;                 // 16-col accum tiles per wave
  __shared__ u16 As[128 * BK];
  __shared__ u16 Bs[BN * BK];
  int t = threadIdx.x;
  int blk = blockIdx.x;
  int pair = 0;
  if constexpr (NPAIR == 2) { pair = blk & 1; blk >>= 1; }
  const u16* A        = pair ? A1 : A0;
  const u16* Wp       = pair ? W1 : W0;
  const float* bias   = pair ? bias1 : bias0;
  u16* outb           = pair ? outb1 : outb0;
  float2* st          = pair ? st1 : st0;
  const float* addpts = pair ? addpts1 : addpts0;
  float* ptsout       = pair ? ptsout1 : ptsout0;
  int nv = pair ? nv1 : nv0;
  int cb = pair ? cb1 : cb0;

  int bm = blk & 127, bn = blk >> 7;
  int lane = t & 63, wave = t >> 6;
  int wm = (wave & 1) << 6;
  int wn = (wave >> 1) * (BN / 2);
  int quad = lane >> 4, r16 = lane & 15;

  floatx4 acc[4][NJ];
  #pragma unroll
  for (int i = 0; i < 4; ++i)
    #pragma unroll
    for (int j = 0; j < NJ; ++j)
      acc[i][j] = (floatx4){0.f, 0.f, 0.f, 0.f};

  if constexpr (BK == 64) {
    // staging: 8 chunks/row; thread t covers (row = 32k + t>>3, slot = t&7)
    int sub = t >> 3;                 // 0..31
    int cq = (t & 7) ^ (sub & 7);     // XOR-swizzled global chunk for this slot
    int abase[4];
    #pragma unroll
    for (int k = 0; k < 4; ++k) {
      int m = bm * 128 + k * 32 + sub;
      if constexpr (AMODE == 1) {
        int b = m >> 12, p = m & 4095;
        abase[k] = ((b * 66 + (p >> 6)) * 66 + (p & 63)) * 256 + cq * 8;
      } else {
        abase[k] = m * KSZ + cq * 8;
      }
    }
    const u16* wg = Wp + (size_t)(bn * BN + sub) * KSZ + cq * 8;

    for (int s = 0; s < KSZ / 64; ++s) {
      int d;
      if constexpr (AMODE == 1) {
        int kk = s >> 2;                 // 0..8
        int c0 = (s & 3) << 6;           // 0..192
        int ky = kk / 3, kx = kk - ky * 3;
        d = ((ky * 66 + kx) << 8) + c0;
      } else {
        d = s * 64;
      }
      #pragma unroll
      for (int k = 0; k < 4; ++k)
        gl_lds16(A + abase[k] + d, &As[k * 2048 + t * 8]);
      #pragma unroll
      for (int k = 0; k < BN / 32; ++k)
        gl_lds16(wg + (size_t)(k * 32) * KSZ + s * 64, &Bs[k * 2048 + t * 8]);
      __syncthreads();
      short8 af[2][4], bfr[2][NJ];
      #pragma unroll
      for (int ks = 0; ks < 2; ++ks) {
        #pragma unroll
        for (int i = 0; i < 4; ++i)
          af[ks][i] = *(const short8*)&As[lds_slot64(wm + i * 16 + r16, ks * 4 + quad)];
        #pragma unroll
        for (int j = 0; j < NJ; ++j)
          bfr[ks][j] = *(const short8*)&Bs[lds_slot64(wn + j * 16 + r16, ks * 4 + quad)];
      }
      #pragma unroll
      for (int ks = 0; ks < 2; ++ks)
        #pragma unroll
        for (int i = 0; i < 4; ++i)
          #pragma unroll
          for (int j = 0; j < NJ; ++j)
            acc[i][j] = __builtin_amdgcn_mfma_f32_16x16x32_bf16(af[ks][i], bfr[ks][j], acc[i][j], 0, 0, 0);
      __syncthreads();
    }
  } else {
    // BK=32 path (R4-verified): 4 chunks/row
    int row = t >> 2;
    int chunkS = (t & 3) ^ ((t >> 3) & 3);
    int m0 = bm * 128 + row, m1 = m0 + 64;
    int abase0, abase1;
    if constexpr (AMODE == 1) {
      int b0 = m0 >> 12, p0 = m0 & 4095;
      int b1 = m1 >> 12, p1 = m1 & 4095;
      abase0 = ((b0 * 66 + (p0 >> 6)) * 66 + (p0 & 63)) * 256 + chunkS * 8;
      abase1 = ((b1 * 66 + (p1 >> 6)) * 66 + (p1 & 63)) * 256 + chunkS * 8;
    } else {
      abase0 = m0 * KSZ + chunkS * 8;
      abase1 = m1 * KSZ + chunkS * 8;
    }
    const u16* wg = Wp + (size_t)(bn * BN + row) * KSZ + chunkS * 8;

    for (int s = 0; s < KSZ / 32; ++s) {
      int d;
      if constexpr (AMODE == 1) {
        int kk = s >> 3;
        int c0 = (s & 7) << 5;
        int ky = kk / 3, kx = kk - ky * 3;
        d = ((ky * 66 + kx) << 8) + c0;
      } else {
        d = s * 32;
      }
      gl_lds16(A + abase0 + d, &As[t * 8]);
      gl_lds16(A + abase1 + d, &As[2048 + t * 8]);
      gl_lds16(wg + s * 32, &Bs[t * 8]);
      if constexpr (BN == 128)
        gl_lds16(wg + (size_t)64 * KSZ + s * 32, &Bs[2048 + t * 8]);
      __syncthreads();
      short8 af[4], bfr[NJ];
      #pragma unroll
      for (int i = 0; i < 4; ++i)
        af[i] = *(const short8*)&As[lds_slot32(wm + i * 16 + r16, quad)];
      #pragma unroll
      for (int j = 0; j < NJ; ++j)
        bfr[j] = *(const short8*)&Bs[lds_slot32(wn + j * 16 + r16, quad)];
      #pragma unroll
      for (int i = 0; i < 4; ++i)
        #pragma unroll
        for (int j = 0; j < NJ; ++j)
          acc[i][j] = __builtin_amdgcn_mfma_f32_16x16x32_bf16(af[i], bfr[j], acc[i][j], 0, 0, 0);
      __syncthreads();
    }
  }

  #pragma unroll
  for (int j = 0; j < NJ; ++j) {
    int gn = bn * BN + wn + j * 16 + r16;
    float s = 0.f, s2 = 0.f;
    #pragma unroll
    for (int i = 0; i < 4; ++i) {
      #pragma unroll
      for (int r = 0; r < 4; ++r) {
        int gm = bm * 128 + wm + i * 16 + quad * 4 + r;
        float v = acc[i][j][r];
        if constexpr (EP == 0) {
          outb[(size_t)gm * 256 + gn] = f2bf(v);
          s += v; s2 += v * v;
        } else if constexpr (EP == 1) {
          outb[(size_t)gm * 256 + gn] = f2bf(fmaxf(v + bias[gn], 0.f));
        } else if constexpr (EP == 2) {
          outb[(size_t)gm * 256 + gn] = f2bf(fmaxf(v, 0.f));
        } else {
          if (gn < nv) {
            v += bias[gn];
            if (addpts) v += addpts[(size_t)gm * 18 + gn];
            if (ptsout) ptsout[(size_t)gm * 18 + gn] = v;
            int bb = gm >> 12, p = gm & 4095;
            outf[(size_t)((bb * 116 + cb + gn) << 12) + p] = v;
          }
        }
      }
    }
    if constexpr (EP == 0) {
      // reduce lanes differing in bits {0,1,2,4,5}; keep bit3 (8-ch group)
      s += __shfl_xor(s, 1);  s2 += __shfl_xor(s2, 1);
      s += __shfl_xor(s, 2);  s2 += __shfl_xor(s2, 2);
      s += __shfl_xor(s, 4);  s2 += __shfl_xor(s2, 4);
      s += __shfl_xor(s, 16); s2 += __shfl_xor(s2, 16);
      s += __shfl_xor(s, 32); s2 += __shfl_xor(s2, 32);
      if ((lane & 55) == 0) {
        float2* sp = st + ((bm >> 5) * 32) + (gn >> 3);
        atomicAdd(&sp->x, s);
        atomicAdd(&sp->y, s2);
      }
    }
  }
}

// ---------------------------------------------------------------------------
extern "C" void kernel_launch(void* const* d_in, const int* in_sizes, int n_in,
                              void* d_out, int out_size, void* d_ws, size_t ws_size,
                              hipStream_t stream) {
  (void)in_sizes; (void)n_in; (void)out_size;
  const float* features    = (const float*)d_in[0];
  const float* cls_w       = (const float*)d_in[1];
  const float* reg_w       = (const float*)d_in[2];
  const float* cls_gn_w    = (const float*)d_in[3];
  const float* cls_gn_b    = (const float*)d_in[4];
  const float* reg_gn_w    = (const float*)d_in[5];
  const float* reg_gn_b    = (const float*)d_in[6];
  const float* init_conv_w = (const float*)d_in[7];
  const float* init_conv_b = (const float*)d_in[8];
  const float* init_out_w  = (const float*)d_in[9];
  const float* init_out_b  = (const float*)d_in[10];
  const float* cls_dcn_w   = (const float*)d_in[11];
  const float* cls_out_w   = (const float*)d_in[12];
  const float* cls_out_b   = (const float*)d_in[13];
  const float* ref_dcn_w   = (const float*)d_in[14];
  const float* ref_out_w   = (const float*)d_in[15];
  const float* ref_out_b   = (const float*)d_in[16];
  float* out = (float*)d_out;

  char* ws = (char*)d_ws;
  size_t off = 0;
  auto alloc = [&](size_t bytes) {
    char* p = ws + off;
    off += (bytes + 255) & ~(size_t)255;
    return p;
  };
  u16* wpack      = (u16*)alloc((size_t)9 * WSTEP * 2);
  u16* w1         = (u16*)alloc((size_t)3 * 32768 * 2);
  u16* xpad       = (u16*)alloc(PADB);     // 5 pads contiguous (PADB % 256 == 0)
  u16* cpadA      = (u16*)alloc(PADB);
  u16* cpadB      = (u16*)alloc(PADB);
  u16* rpadA      = (u16*)alloc(PADB);
  u16* rpadB      = (u16*)alloc(PADB);
  float* ptsbuf   = (float*)alloc((size_t)MTOT * 18 * 4);
  float2* statsAll= (float2*)alloc(3 * 256 * sizeof(float2));
  u16* initf      = (u16*)alloc((size_t)MTOT * 256 * 2);
  u16* dcnout     = (u16*)alloc((size_t)2 * MTOT * 256 * 2);
  // union region: cstage [2][M][256] bf16 (towers) then adcn [M][2304] bf16 (dcn)
  char* unionReg  = alloc((size_t)MTOT * 2304 * 2);
  u16* cstage     = (u16*)unionReg;
  u16* adcn       = (u16*)unionReg;
  u16* adcn2      = (u16*)alloc((size_t)MTOT * 2304 * 2);   // only used if ws allows
  bool paired_dcn = (off <= ws_size);

  (void)hipMemsetAsync(statsAll, 0, 3 * 256 * sizeof(float2), stream);
  setup_all<<<23444, 256, 0, stream>>>(cls_w, reg_w, init_conv_w, cls_dcn_w, ref_dcn_w,
                                       init_out_w, cls_out_w, ref_out_w, features,
                                       wpack, w1, xpad);

  // towers, paired (cls=pair0, reg=pair1): 3 layers of conv3x3+GN+relu
  const u16* curC = xpad; const u16* curR = xpad;
  u16* nxtC = cpadA; u16* altC = cpadB;
  u16* nxtR = rpadA; u16* altR = rpadB;
  for (int i = 0; i < 3; ++i) {
    gemm_kernel<1, 0, 2304, 64, 64, 2><<<1024, 256, 0, stream>>>(
        curC, curR, wpack + (size_t)i * WSTEP, wpack + (size_t)(3 + i) * WSTEP,
        nullptr, nullptr, cstage, cstage + (size_t)MTOT * 256,
        statsAll + i * 256, statsAll + i * 256 + 128,
        nullptr, nullptr, nullptr, nullptr, nullptr, 0, 0, 0, 0);
    gn_apply2<<<8192, 256, 0, stream>>>(cstage, statsAll + i * 256,
        cls_gn_w + i * 256, cls_gn_b + i * 256, reg_gn_w + i * 256, reg_gn_b + i * 256,
        nxtC, nxtR);
    curC = nxtC; { u16* tmp = nxtC; nxtC = altC; altC = tmp; }
    curR = nxtR; { u16* tmp = nxtR; nxtR = altR; altR = tmp; }
  }
  const u16* cls_feat = curC;   // cpadA
  const u16* reg_feat = curR;   // rpadA

  // init branch: relu(conv3x3 + b) -> initf; 1x1 -> pts_init (out ch 80..97 + ptsbuf)
  gemm_kernel<1, 1, 2304, 64, 64, 1><<<512, 256, 0, stream>>>(
      reg_feat, nullptr, wpack + (size_t)6 * WSTEP, nullptr,
      init_conv_b, nullptr, initf, nullptr, nullptr, nullptr,
      nullptr, nullptr, nullptr, nullptr, nullptr, 0, 0, 0, 0);
  gemm_kernel<0, 3, 256, 128, 32, 1><<<128, 256, 0, stream>>>(
      initf, nullptr, w1, nullptr, init_out_b, nullptr,
      nullptr, nullptr, nullptr, nullptr, out,
      nullptr, nullptr, ptsbuf, nullptr, 18, 0, 80, 0);

  if (paired_dcn) {
    dcn_sample2<<<2048, 256, 0, stream>>>(cls_feat, reg_feat, ptsbuf, adcn, adcn2);
    gemm_kernel<0, 2, 2304, 64, 64, 2><<<1024, 256, 0, stream>>>(
        adcn, adcn2, wpack + (size_t)7 * WSTEP, wpack + (size_t)8 * WSTEP,
        nullptr, nullptr, dcnout, dcnout + (size_t)MTOT * 256, nullptr, nullptr,
        nullptr, nullptr, nullptr, nullptr, nullptr, 0, 0, 0, 0);
  } else {
    dcn_sample2<<<1024, 256, 0, stream>>>(cls_feat, cls_feat, ptsbuf, adcn, adcn);
    gemm_kernel<0, 2, 2304, 64, 64, 1><<<512, 256, 0, stream>>>(
        adcn, nullptr, wpack + (size_t)7 * WSTEP, nullptr,
        nullptr, nullptr, dcnout, nullptr, nullptr, nullptr,
        nullptr, nullptr, nullptr, nullptr, nullptr, 0, 0, 0, 0);
    dcn_sample2<<<1024, 256, 0, stream>>>(reg_feat, reg_feat, ptsbuf, adcn, adcn);
    gemm_kernel<0, 2, 2304, 64, 64, 1><<<512, 256, 0, stream>>>(
        adcn, nullptr, wpack + (size_t)8 * WSTEP, nullptr,
        nullptr, nullptr, dcnout + (size_t)MTOT * 256, nullptr, nullptr, nullptr,
        nullptr, nullptr, nullptr, nullptr, nullptr, 0, 0, 0, 0);
  }

  // final heads, paired: cls (80 ch at 0), refine (18 ch at 98, + pts_init)
  gemm_kernel<0, 3, 256, 128, 32, 2><<<256, 256, 0, stream>>>(
      dcnout, dcnout + (size_t)MTOT * 256, w1 + 32768, w1 + 2 * 32768,
      cls_out_b, ref_out_b, nullptr, nullptr, nullptr, nullptr, out,
      nullptr, ptsbuf, nullptr, nullptr, 80, 18, 0, 98);
}